// Round 2
// baseline (1326.138 us; speedup 1.0000x reference)
//
#include <hip/hip_runtime.h>

#define N_NODES 20000
#define N_EDGES 640000
#define DIM 128
#define NGRAPH 128
#define NLAYER 5
#define EDIM 7
#define TWO_D 256

typedef __bf16 bf16x8 __attribute__((ext_vector_type(8)));
typedef float  f32x4  __attribute__((ext_vector_type(4)));

__device__ __forceinline__ f32x4 mfma16(bf16x8 a, bf16x8 b, f32x4 c) {
  return __builtin_amdgcn_mfma_f32_16x16x32_bf16(a, b, c, 0, 0, 0);
}

// ---------------- CSR build ----------------
__global__ void k_hist(const int* __restrict__ dst, int* __restrict__ counts) {
  int e = blockIdx.x * blockDim.x + threadIdx.x;
  if (e < N_EDGES) atomicAdd(&counts[dst[e]], 1);
}

__global__ __launch_bounds__(1024) void k_scan(const int* __restrict__ counts,
                                               int* __restrict__ offsets) {
  __shared__ int sd[1024];
  __shared__ int run_s;
  int tid = threadIdx.x;
  if (tid == 0) run_s = 0;
  __syncthreads();
  for (int base = 0; base < N_NODES; base += 1024) {
    int i = base + tid;
    int v = (i < N_NODES) ? counts[i] : 0;
    sd[tid] = v;
    __syncthreads();
    for (int ofs = 1; ofs < 1024; ofs <<= 1) {
      int t = (tid >= ofs) ? sd[tid - ofs] : 0;
      __syncthreads();
      sd[tid] += t;
      __syncthreads();
    }
    int incl = sd[tid];
    int run = run_s;
    if (i < N_NODES) offsets[i] = run + incl - v;
    __syncthreads();
    if (tid == 0) run_s = run + sd[1023];
    __syncthreads();
  }
  if (tid == 0) offsets[N_NODES] = run_s;
}

__global__ void k_fill(const int* __restrict__ srcArr, const int* __restrict__ dstArr,
                       const int* __restrict__ offsets, int* __restrict__ cursor,
                       int* __restrict__ csr_src, int* __restrict__ csr_eid) {
  int e = blockIdx.x * blockDim.x + threadIdx.x;
  if (e >= N_EDGES) return;
  int d = dstArr[e];
  int p = offsets[d] + atomicAdd(&cursor[d], 1);
  csr_src[p] = srcArr[e];
  csr_eid[p] = e;
}

__global__ void k_gs(const int* __restrict__ batch, int* __restrict__ gs) {
  int g = threadIdx.x;
  if (g > NGRAPH) return;
  if (g == NGRAPH) { gs[NGRAPH] = N_NODES; return; }
  int lo = 0, hi = N_NODES;
  while (lo < hi) { int mid = (lo + hi) >> 1; if (batch[mid] < g) lo = mid + 1; else hi = mid; }
  gs[g] = lo;
}

// ---------------- weight convert/transpose with hi/lo split ----------------
// src: [layers][K][C] f32 row-major -> dst_{hi,lo}: [layers][C][K] bf16
__global__ void k_convT2(const float* __restrict__ src, __bf16* __restrict__ dst_hi,
                         __bf16* __restrict__ dst_lo, int K, int C, int layers) {
  int total = layers * K * C;
  for (int i = blockIdx.x * blockDim.x + threadIdx.x; i < total;
       i += gridDim.x * blockDim.x) {
    int l = i / (K * C);
    int rem = i - l * K * C;
    int k = rem / C;
    int c = rem - k * C;
    float v = src[i];
    __bf16 hi = (__bf16)v;
    __bf16 lo = (__bf16)(v - (float)hi);
    size_t o = (size_t)l * K * C + (size_t)c * K + k;
    dst_hi[o] = hi;
    dst_lo[o] = lo;
  }
}

__global__ void k_vninit(const float* __restrict__ vn_emb, float* __restrict__ vn) {
  int i = blockIdx.x * blockDim.x + threadIdx.x;
  if (i < NGRAPH * DIM) vn[i] = vn_emb[i & (DIM - 1)];
}

// ---------------- encoder GEMM: h_in = x @ encW + enc_b + vn_emb ----------------
__global__ __launch_bounds__(128) void k_enc(const float* __restrict__ x,
    const __bf16* __restrict__ encT_hi, const __bf16* __restrict__ encT_lo,
    const float* __restrict__ enc_b, const float* __restrict__ vn_emb,
    float* __restrict__ h_in) {
  int lane = threadIdx.x & 63, wid = threadIdx.x >> 6;
  int rbase = blockIdx.x * 32 + wid * 16;
  int r = rbase + (lane & 15);
  int ko = (lane >> 4) * 8;
  const float* xr = x + (size_t)r * DIM;
  bf16x8 a_hi[4], a_lo[4];
#pragma unroll
  for (int ks = 0; ks < 4; ++ks) {
    f32x4 v0 = *(const f32x4*)(xr + ks * 32 + ko);
    f32x4 v1 = *(const f32x4*)(xr + ks * 32 + ko + 4);
    bf16x8 th, tl;
#pragma unroll
    for (int j = 0; j < 4; ++j) {
      th[j] = (__bf16)v0[j];     tl[j] = (__bf16)(v0[j] - (float)th[j]);
      th[4+j] = (__bf16)v1[j];   tl[4+j] = (__bf16)(v1[j] - (float)th[4+j]);
    }
    a_hi[ks] = th; a_lo[ks] = tl;
  }
  const f32x4 fz = {0.f, 0.f, 0.f, 0.f};
  f32x4 acc[8];
#pragma unroll
  for (int nf = 0; nf < 8; ++nf) acc[nf] = fz;
#pragma unroll
  for (int nf = 0; nf < 8; ++nf) {
    size_t wrow = (size_t)(nf * 16 + (lane & 15)) * DIM + ko;
    const __bf16* bh = encT_hi + wrow;
    const __bf16* bl = encT_lo + wrow;
#pragma unroll
    for (int ks = 0; ks < 4; ++ks) {
      bf16x8 wh = *(const bf16x8*)(bh + ks * 32);
      bf16x8 wl = *(const bf16x8*)(bl + ks * 32);
      acc[nf] = mfma16(a_hi[ks], wh, acc[nf]);
      acc[nf] = mfma16(a_lo[ks], wh, acc[nf]);
      acc[nf] = mfma16(a_hi[ks], wl, acc[nf]);
    }
  }
  int c0 = lane & 15;
  int rr = rbase + (lane >> 4) * 4;
#pragma unroll
  for (int nf = 0; nf < 8; ++nf) {
    int c = nf * 16 + c0;
    float bias = enc_b[c] + vn_emb[c];
#pragma unroll
    for (int j = 0; j < 4; ++j)
      h_in[(size_t)(rr + j) * DIM + c] = acc[nf][j] + bias;
  }
}

// ---------------- per-graph pool: pooled = segsum(h_in) + vn ----------------
__global__ __launch_bounds__(128) void k_pool(const float* __restrict__ h_in,
    const int* __restrict__ gs, const float* __restrict__ vn,
    float* __restrict__ pooled) {
  int g = blockIdx.x, d = threadIdx.x;
  float acc = vn[g * DIM + d];
  int e = gs[g + 1];
  for (int n = gs[g]; n < e; ++n) acc += h_in[(size_t)n * DIM + d];
  pooled[g * DIM + d] = acc;
}

// ---------------- GIN aggregation -> z (hi/lo split) ----------------
__global__ __launch_bounds__(128) void k_agg(const float* __restrict__ h_in,
    const int* __restrict__ offsets, const int* __restrict__ csr_src,
    const int* __restrict__ csr_eid, const float* __restrict__ edge_attr,
    const float* __restrict__ eW, const float* __restrict__ eB,
    const float* __restrict__ eps, int l,
    __bf16* __restrict__ z_hi, __bf16* __restrict__ z_lo) {
  __shared__ float ewl[EDIM * DIM];
  __shared__ float ebl[DIM];
  int d = threadIdx.x;
#pragma unroll
  for (int k = 0; k < EDIM; ++k) ewl[k * DIM + d] = eW[k * DIM + d];
  ebl[d] = eB[d];
  __syncthreads();
  int n = blockIdx.x;
  int off = offsets[n], end = offsets[n + 1];
  float acc = 0.f;
  for (int i = off; i < end; ++i) {
    int s = csr_src[i];
    int e = csr_eid[i];
    const float* ea = edge_attr + (size_t)e * EDIM;
    float em = ebl[d];
#pragma unroll
    for (int k = 0; k < EDIM; ++k) em = fmaf(ea[k], ewl[k * DIM + d], em);
    float m = h_in[(size_t)s * DIM + d] + em;
    acc += fmaxf(m, 0.f);
  }
  float epsv = 1.f + eps[l];
  float hs = h_in[(size_t)n * DIM + d];
  float v = epsv * hs + acc;
  __bf16 hi = (__bf16)v;
  z_hi[(size_t)n * DIM + d] = hi;
  z_lo[(size_t)n * DIM + d] = (__bf16)(v - (float)hi);
}

// ---------------- GEMM1: y1 = z @ W1 + b1 (+ BN1 stats), y1 f32 ----------------
__global__ __launch_bounds__(128) void k_gemm1(const __bf16* __restrict__ z_hi,
    const __bf16* __restrict__ z_lo,
    const __bf16* __restrict__ W1T_hi, const __bf16* __restrict__ W1T_lo,
    const float* __restrict__ b1,
    float* __restrict__ y1, float* __restrict__ sum1, float* __restrict__ sq1) {
  int lane = threadIdx.x & 63, wid = threadIdx.x >> 6;
  int rbase = blockIdx.x * 32 + wid * 16;
  int r = rbase + (lane & 15);
  int ko = (lane >> 4) * 8;
  bf16x8 a_hi[4], a_lo[4];
#pragma unroll
  for (int ks = 0; ks < 4; ++ks) {
    a_hi[ks] = *(const bf16x8*)(z_hi + (size_t)r * DIM + ks * 32 + ko);
    a_lo[ks] = *(const bf16x8*)(z_lo + (size_t)r * DIM + ks * 32 + ko);
  }
  const f32x4 fz = {0.f, 0.f, 0.f, 0.f};
  f32x4 acc[16];
#pragma unroll
  for (int nf = 0; nf < 16; ++nf) acc[nf] = fz;
#pragma unroll
  for (int nf = 0; nf < 16; ++nf) {
    size_t wrow = (size_t)(nf * 16 + (lane & 15)) * DIM + ko;
    const __bf16* bh = W1T_hi + wrow;
    const __bf16* bl = W1T_lo + wrow;
#pragma unroll
    for (int ks = 0; ks < 4; ++ks) {
      bf16x8 wh = *(const bf16x8*)(bh + ks * 32);
      bf16x8 wl = *(const bf16x8*)(bl + ks * 32);
      acc[nf] = mfma16(a_hi[ks], wh, acc[nf]);
      acc[nf] = mfma16(a_lo[ks], wh, acc[nf]);
      acc[nf] = mfma16(a_hi[ks], wl, acc[nf]);
    }
  }
  int c0 = lane & 15;
  int rr = rbase + (lane >> 4) * 4;
  int rep = blockIdx.x & 7;
#pragma unroll
  for (int nf = 0; nf < 16; ++nf) {
    int c = nf * 16 + c0;
    float bias = b1[c];
    float s = 0.f, q = 0.f;
#pragma unroll
    for (int j = 0; j < 4; ++j) {
      float v = acc[nf][j] + bias;
      y1[(size_t)(rr + j) * TWO_D + c] = v;
      s += v; q += v * v;
    }
    s += __shfl_xor(s, 16); s += __shfl_xor(s, 32);
    q += __shfl_xor(q, 16); q += __shfl_xor(q, 32);
    if (lane < 16) {
      atomicAdd(&sum1[rep * TWO_D + c], s);
      atomicAdd(&sq1[rep * TWO_D + c], q);
    }
  }
}

// ---------------- BN finalize: scale/shift from sums ----------------
__global__ void k_fin(float* __restrict__ sum, float* __restrict__ sq,
    const float* __restrict__ g_, const float* __restrict__ b_,
    float* __restrict__ scale, float* __restrict__ shift, int C, float invN) {
  int c = threadIdx.x;
  if (c >= C) return;
  float s = 0.f, q = 0.f;
#pragma unroll
  for (int rep = 0; rep < 8; ++rep) {
    s += sum[rep * C + c]; sum[rep * C + c] = 0.f;
    q += sq[rep * C + c];  sq[rep * C + c]  = 0.f;
  }
  float m = s * invN;
  float var = q * invN - m * m;
  float a = g_[c] / sqrtf(var + 1e-5f);
  scale[c] = a;
  shift[c] = b_[c] - m * a;
}

// ---------------- GEMM2: y2 = relu(bn1(y1)) @ W2 + b2 (+ BN2 stats) ----------------
__global__ __launch_bounds__(128) void k_gemm2(const float* __restrict__ y1,
    const __bf16* __restrict__ W2T_hi, const __bf16* __restrict__ W2T_lo,
    const float* __restrict__ b2,
    const float* __restrict__ scale1, const float* __restrict__ shift1,
    float* __restrict__ y2, float* __restrict__ sum2, float* __restrict__ sq2) {
  int lane = threadIdx.x & 63, wid = threadIdx.x >> 6;
  int rbase = blockIdx.x * 32 + wid * 16;
  int r = rbase + (lane & 15);
  int ko = (lane >> 4) * 8;
  bf16x8 a_hi[8], a_lo[8];
#pragma unroll
  for (int ks = 0; ks < 8; ++ks) {
    int kb = ks * 32 + ko;
    f32x4 r0 = *(const f32x4*)(y1 + (size_t)r * TWO_D + kb);
    f32x4 r1 = *(const f32x4*)(y1 + (size_t)r * TWO_D + kb + 4);
    f32x4 sc0 = *(const f32x4*)(scale1 + kb);
    f32x4 sc1 = *(const f32x4*)(scale1 + kb + 4);
    f32x4 sh0 = *(const f32x4*)(shift1 + kb);
    f32x4 sh1 = *(const f32x4*)(shift1 + kb + 4);
    bf16x8 th, tl;
#pragma unroll
    for (int j = 0; j < 4; ++j) {
      float v0 = fmaxf(r0[j] * sc0[j] + sh0[j], 0.f);
      float v1 = fmaxf(r1[j] * sc1[j] + sh1[j], 0.f);
      th[j] = (__bf16)v0;     tl[j] = (__bf16)(v0 - (float)th[j]);
      th[4+j] = (__bf16)v1;   tl[4+j] = (__bf16)(v1 - (float)th[4+j]);
    }
    a_hi[ks] = th; a_lo[ks] = tl;
  }
  const f32x4 fz = {0.f, 0.f, 0.f, 0.f};
  f32x4 acc[8];
#pragma unroll
  for (int nf = 0; nf < 8; ++nf) acc[nf] = fz;
#pragma unroll
  for (int nf = 0; nf < 8; ++nf) {
    size_t wrow = (size_t)(nf * 16 + (lane & 15)) * TWO_D + ko;
    const __bf16* bh = W2T_hi + wrow;
    const __bf16* bl = W2T_lo + wrow;
#pragma unroll
    for (int ks = 0; ks < 8; ++ks) {
      bf16x8 wh = *(const bf16x8*)(bh + ks * 32);
      bf16x8 wl = *(const bf16x8*)(bl + ks * 32);
      acc[nf] = mfma16(a_hi[ks], wh, acc[nf]);
      acc[nf] = mfma16(a_lo[ks], wh, acc[nf]);
      acc[nf] = mfma16(a_hi[ks], wl, acc[nf]);
    }
  }
  int c0 = lane & 15;
  int rr = rbase + (lane >> 4) * 4;
  int rep = blockIdx.x & 7;
#pragma unroll
  for (int nf = 0; nf < 8; ++nf) {
    int c = nf * 16 + c0;
    float bias = b2[c];
    float s = 0.f, q = 0.f;
#pragma unroll
    for (int j = 0; j < 4; ++j) {
      float v = acc[nf][j] + bias;
      y2[(size_t)(rr + j) * DIM + c] = v;
      s += v; q += v * v;
    }
    s += __shfl_xor(s, 16); s += __shfl_xor(s, 32);
    q += __shfl_xor(q, 16); q += __shfl_xor(q, 32);
    if (lane < 16) {
      atomicAdd(&sum2[rep * DIM + c], s);
      atomicAdd(&sq2[rep * DIM + c], q);
    }
  }
}

// ---------------- virtual-node small GEMM / BN (f32, exact) ----------------
__global__ void k_vgemm(const float* __restrict__ in, const float* __restrict__ W,
    const float* __restrict__ bias, float* __restrict__ out, int K, int C) {
  __shared__ float row[TWO_D];
  int g = blockIdx.x;
  for (int k = threadIdx.x; k < K; k += blockDim.x) row[k] = in[g * K + k];
  __syncthreads();
  int c = threadIdx.x;
  if (c >= C) return;
  float acc = bias[c];
  for (int k = 0; k < K; ++k) acc = fmaf(row[k], W[k * C + c], acc);
  out[g * C + c] = acc;
}

__global__ void k_vbn(float* __restrict__ data, const float* __restrict__ g_,
    const float* __restrict__ b_, float* __restrict__ out, int C) {
  int c = threadIdx.x;
  if (c >= C) return;
  float s = 0.f, q = 0.f;
  for (int r = 0; r < NGRAPH; ++r) { float v = data[r * C + c]; s += v; q += v * v; }
  float m = s * (1.f / NGRAPH);
  float var = q * (1.f / NGRAPH) - m * m;
  float a = g_[c] / sqrtf(var + 1e-5f);
  float sh = b_[c] - m * a;
  for (int r = 0; r < NGRAPH; ++r)
    out[r * C + c] = fmaxf(data[r * C + c] * a + sh, 0.f);
}

// ---------------- fused BN2 + relu + vn gather -> next h_in ----------------
__global__ void k_bn2hin(const float* __restrict__ y2, const float* __restrict__ scale2,
    const float* __restrict__ shift2, const float* __restrict__ vn,
    const int* __restrict__ batch, float* __restrict__ h_in) {
  int idx = blockIdx.x * blockDim.x + threadIdx.x;
  if (idx >= N_NODES * (DIM / 4)) return;
  int c4 = idx & 31;
  int row = idx >> 5;
  f32x4 y = ((const f32x4*)y2)[idx];
  f32x4 sc = ((const f32x4*)scale2)[c4];
  f32x4 sh = ((const f32x4*)shift2)[c4];
  int b = batch[row];
  f32x4 v = ((const f32x4*)vn)[b * 32 + c4];
  f32x4 o;
#pragma unroll
  for (int j = 0; j < 4; ++j) o[j] = fmaxf(y[j] * sc[j] + sh[j], 0.f) + v[j];
  ((f32x4*)h_in)[idx] = o;
}

__global__ void k_out(const float* __restrict__ y2, const float* __restrict__ scale2,
    const float* __restrict__ shift2, float* __restrict__ out) {
  int idx = blockIdx.x * blockDim.x + threadIdx.x;
  if (idx >= N_NODES * (DIM / 4)) return;
  int c4 = idx & 31;
  f32x4 y = ((const f32x4*)y2)[idx];
  f32x4 sc = ((const f32x4*)scale2)[c4];
  f32x4 sh = ((const f32x4*)shift2)[c4];
  f32x4 o;
#pragma unroll
  for (int j = 0; j < 4; ++j) o[j] = y[j] * sc[j] + sh[j];
  ((f32x4*)out)[idx] = o;
}

// ---------------- host ----------------
extern "C" void kernel_launch(void* const* d_in, const int* in_sizes, int n_in,
                              void* d_out, int out_size, void* d_ws, size_t ws_size,
                              hipStream_t stream) {
  const float* x         = (const float*)d_in[0];
  const float* edge_attr = (const float*)d_in[1];
  const int*   edge_index= (const int*)d_in[2];
  const int*   batch     = (const int*)d_in[3];
  const float* enc_W     = (const float*)d_in[4];
  const float* enc_b     = (const float*)d_in[5];
  const float* vn_emb    = (const float*)d_in[6];
  const float* eps       = (const float*)d_in[7];
  const float* edge_W    = (const float*)d_in[8];
  const float* edge_b    = (const float*)d_in[9];
  const float* mlp_W1    = (const float*)d_in[10];
  const float* mlp_b1    = (const float*)d_in[11];
  const float* mlp_bn1_g = (const float*)d_in[12];
  const float* mlp_bn1_b = (const float*)d_in[13];
  const float* mlp_W2    = (const float*)d_in[14];
  const float* mlp_b2    = (const float*)d_in[15];
  const float* bn_g      = (const float*)d_in[16];
  const float* bn_b      = (const float*)d_in[17];
  const float* vn_W1     = (const float*)d_in[18];
  const float* vn_b1     = (const float*)d_in[19];
  const float* vn_bn1_g  = (const float*)d_in[20];
  const float* vn_bn1_b  = (const float*)d_in[21];
  const float* vn_W2     = (const float*)d_in[22];
  const float* vn_b2     = (const float*)d_in[23];
  const float* vn_bn2_g  = (const float*)d_in[24];
  const float* vn_bn2_b  = (const float*)d_in[25];

  char* wsb = (char*)d_ws;
  size_t off = 0;
  auto take = [&](size_t bytes) -> void* {
    void* p = wsb + off;
    off += (bytes + 255) & ~(size_t)255;
    return p;
  };
  float*  h_in    = (float*)take((size_t)N_NODES * DIM * 4);
  float*  y2      = (float*)take((size_t)N_NODES * DIM * 4);
  float*  y1      = (float*)take((size_t)N_NODES * TWO_D * 4);
  __bf16* z_hi    = (__bf16*)take((size_t)N_NODES * DIM * 2);
  __bf16* z_lo    = (__bf16*)take((size_t)N_NODES * DIM * 2);
  int*    csr_src = (int*)take((size_t)N_EDGES * 4);
  int*    csr_eid = (int*)take((size_t)N_EDGES * 4);
  int*    counts  = (int*)take((size_t)2 * N_NODES * 4);
  int*    cursor  = counts + N_NODES;
  int*    offsets = (int*)take((size_t)(N_NODES + 1) * 4);
  int*    gs      = (int*)take((size_t)(NGRAPH + 1) * 4);
  float*  pooled  = (float*)take((size_t)NGRAPH * DIM * 4);
  float*  tv      = (float*)take((size_t)NGRAPH * TWO_D * 4);
  float*  vv      = (float*)take((size_t)NGRAPH * DIM * 4);
  float*  vn      = (float*)take((size_t)NGRAPH * DIM * 4);
  float*  sum1    = (float*)take(8 * TWO_D * 4);
  float*  sq1     = (float*)take(8 * TWO_D * 4);
  float*  sum2    = (float*)take(8 * DIM * 4);
  float*  sq2     = (float*)take(8 * DIM * 4);
  float*  scale1  = (float*)take(TWO_D * 4);
  float*  shift1  = (float*)take(TWO_D * 4);
  float*  scale2  = (float*)take(DIM * 4);
  float*  shift2  = (float*)take(DIM * 4);
  __bf16* encT_hi = (__bf16*)take((size_t)DIM * DIM * 2);
  __bf16* encT_lo = (__bf16*)take((size_t)DIM * DIM * 2);
  __bf16* W1T_hi  = (__bf16*)take((size_t)NLAYER * DIM * TWO_D * 2);
  __bf16* W1T_lo  = (__bf16*)take((size_t)NLAYER * DIM * TWO_D * 2);
  __bf16* W2T_hi  = (__bf16*)take((size_t)NLAYER * TWO_D * DIM * 2);
  __bf16* W2T_lo  = (__bf16*)take((size_t)NLAYER * TWO_D * DIM * 2);
  if (off > ws_size) return;

  const int* srcArr = edge_index;
  const int* dstArr = edge_index + N_EDGES;

  hipMemsetAsync(counts, 0, (size_t)2 * N_NODES * 4, stream);
  hipMemsetAsync(sum1, 0, (8 * TWO_D * 2 + 8 * DIM * 2) * 4, stream);

  k_hist<<<N_EDGES / 256, 256, 0, stream>>>(dstArr, counts);
  k_scan<<<1, 1024, 0, stream>>>(counts, offsets);
  k_fill<<<N_EDGES / 256, 256, 0, stream>>>(srcArr, dstArr, offsets, cursor, csr_src, csr_eid);
  k_gs<<<1, 256, 0, stream>>>(batch, gs);
  k_convT2<<<128, 256, 0, stream>>>(enc_W, encT_hi, encT_lo, DIM, DIM, 1);
  k_convT2<<<128, 256, 0, stream>>>(mlp_W1, W1T_hi, W1T_lo, DIM, TWO_D, NLAYER);
  k_convT2<<<128, 256, 0, stream>>>(mlp_W2, W2T_hi, W2T_lo, TWO_D, DIM, NLAYER);
  k_vninit<<<(NGRAPH * DIM) / 256, 256, 0, stream>>>(vn_emb, vn);
  k_enc<<<N_NODES / 32, 128, 0, stream>>>(x, encT_hi, encT_lo, enc_b, vn_emb, h_in);

  for (int l = 0; l < NLAYER; ++l) {
    if (l < NLAYER - 1)
      k_pool<<<NGRAPH, DIM, 0, stream>>>(h_in, gs, vn, pooled);
    k_agg<<<N_NODES, DIM, 0, stream>>>(h_in, offsets, csr_src, csr_eid, edge_attr,
        edge_W + (size_t)l * EDIM * DIM, edge_b + (size_t)l * DIM, eps, l, z_hi, z_lo);
    k_gemm1<<<N_NODES / 32, 128, 0, stream>>>(z_hi, z_lo,
        W1T_hi + (size_t)l * DIM * TWO_D, W1T_lo + (size_t)l * DIM * TWO_D,
        mlp_b1 + (size_t)l * TWO_D, y1, sum1, sq1);
    k_fin<<<1, TWO_D, 0, stream>>>(sum1, sq1, mlp_bn1_g + (size_t)l * TWO_D,
        mlp_bn1_b + (size_t)l * TWO_D, scale1, shift1, TWO_D, 1.f / N_NODES);
    k_gemm2<<<N_NODES / 32, 128, 0, stream>>>(y1,
        W2T_hi + (size_t)l * TWO_D * DIM, W2T_lo + (size_t)l * TWO_D * DIM,
        mlp_b2 + (size_t)l * DIM, scale1, shift1, y2, sum2, sq2);
    k_fin<<<1, DIM, 0, stream>>>(sum2, sq2, bn_g + (size_t)l * DIM,
        bn_b + (size_t)l * DIM, scale2, shift2, DIM, 1.f / N_NODES);
    if (l < NLAYER - 1) {
      k_vgemm<<<NGRAPH, TWO_D, 0, stream>>>(pooled, vn_W1 + (size_t)l * DIM * TWO_D,
          vn_b1 + (size_t)l * TWO_D, tv, DIM, TWO_D);
      k_vbn<<<1, TWO_D, 0, stream>>>(tv, vn_bn1_g + (size_t)l * TWO_D,
          vn_bn1_b + (size_t)l * TWO_D, tv, TWO_D);
      k_vgemm<<<NGRAPH, DIM, 0, stream>>>(tv, vn_W2 + (size_t)l * TWO_D * DIM,
          vn_b2 + (size_t)l * DIM, vv, TWO_D, DIM);
      k_vbn<<<1, DIM, 0, stream>>>(vv, vn_bn2_g + (size_t)l * DIM,
          vn_bn2_b + (size_t)l * DIM, vn, DIM);
      k_bn2hin<<<(N_NODES * 32) / 256, 256, 0, stream>>>(y2, scale2, shift2, vn, batch, h_in);
    } else {
      k_out<<<(N_NODES * 32) / 256, 256, 0, stream>>>(y2, scale2, shift2, (float*)d_out);
    }
  }
}

// Round 3
// 1322.591 us; speedup vs baseline: 1.0027x; 1.0027x over previous
//
#include <hip/hip_runtime.h>

#define N_NODES 20000
#define N_EDGES 640000
#define DIM 128
#define NGRAPH 128
#define NLAYER 5
#define EDIM 7
#define TWO_D 256

typedef __bf16 bf16x8 __attribute__((ext_vector_type(8)));
typedef __bf16 bf16x4 __attribute__((ext_vector_type(4)));
typedef float  f32x4  __attribute__((ext_vector_type(4)));

__device__ __forceinline__ f32x4 mfma16(bf16x8 a, bf16x8 b, f32x4 c) {
  return __builtin_amdgcn_mfma_f32_16x16x32_bf16(a, b, c, 0, 0, 0);
}

// ---------------- CSR build ----------------
__global__ void k_hist(const int* __restrict__ dst, int* __restrict__ counts) {
  int e = blockIdx.x * blockDim.x + threadIdx.x;
  if (e < N_EDGES) atomicAdd(&counts[dst[e]], 1);
}

__global__ __launch_bounds__(1024) void k_scan(const int* __restrict__ counts,
                                               int* __restrict__ offsets) {
  __shared__ int sd[1024];
  __shared__ int run_s;
  int tid = threadIdx.x;
  if (tid == 0) run_s = 0;
  __syncthreads();
  for (int base = 0; base < N_NODES; base += 1024) {
    int i = base + tid;
    int v = (i < N_NODES) ? counts[i] : 0;
    sd[tid] = v;
    __syncthreads();
    for (int ofs = 1; ofs < 1024; ofs <<= 1) {
      int t = (tid >= ofs) ? sd[tid - ofs] : 0;
      __syncthreads();
      sd[tid] += t;
      __syncthreads();
    }
    int incl = sd[tid];
    int run = run_s;
    if (i < N_NODES) offsets[i] = run + incl - v;
    __syncthreads();
    if (tid == 0) run_s = run + sd[1023];
    __syncthreads();
  }
  if (tid == 0) offsets[N_NODES] = run_s;
}

__global__ void k_fill(const int* __restrict__ srcArr, const int* __restrict__ dstArr,
                       const int* __restrict__ offsets, int* __restrict__ cursor,
                       int* __restrict__ csr_src, int* __restrict__ csr_eid) {
  int e = blockIdx.x * blockDim.x + threadIdx.x;
  if (e >= N_EDGES) return;
  int d = dstArr[e];
  int p = offsets[d] + atomicAdd(&cursor[d], 1);
  csr_src[p] = srcArr[e];
  csr_eid[p] = e;
}

__global__ void k_gs(const int* __restrict__ batch, int* __restrict__ gs) {
  int g = threadIdx.x;
  if (g > NGRAPH) return;
  if (g == NGRAPH) { gs[NGRAPH] = N_NODES; return; }
  int lo = 0, hi = N_NODES;
  while (lo < hi) { int mid = (lo + hi) >> 1; if (batch[mid] < g) lo = mid + 1; else hi = mid; }
  gs[g] = lo;
}

// ---------------- weight convert/transpose with hi/lo split ----------------
__global__ void k_convT2(const float* __restrict__ src, __bf16* __restrict__ dst_hi,
                         __bf16* __restrict__ dst_lo, int K, int C, int layers) {
  int total = layers * K * C;
  for (int i = blockIdx.x * blockDim.x + threadIdx.x; i < total;
       i += gridDim.x * blockDim.x) {
    int l = i / (K * C);
    int rem = i - l * K * C;
    int k = rem / C;
    int c = rem - k * C;
    float v = src[i];
    __bf16 hi = (__bf16)v;
    __bf16 lo = (__bf16)(v - (float)hi);
    size_t o = (size_t)l * K * C + (size_t)c * K + k;
    dst_hi[o] = hi;
    dst_lo[o] = lo;
  }
}

__global__ void k_vninit(const float* __restrict__ vn_emb, float* __restrict__ vn) {
  int i = blockIdx.x * blockDim.x + threadIdx.x;
  if (i < NGRAPH * DIM) vn[i] = vn_emb[i & (DIM - 1)];
}

// ---------------- encoder GEMM: h_in = x @ encW + enc_b + vn_emb ----------------
__global__ __launch_bounds__(128) void k_enc(const float* __restrict__ x,
    const __bf16* __restrict__ encT_hi, const __bf16* __restrict__ encT_lo,
    const float* __restrict__ enc_b, const float* __restrict__ vn_emb,
    float* __restrict__ h_in, __bf16* __restrict__ h_bf) {
  int lane = threadIdx.x & 63, wid = threadIdx.x >> 6;
  int rbase = blockIdx.x * 32 + wid * 16;
  int r = rbase + (lane & 15);
  int ko = (lane >> 4) * 8;
  const float* xr = x + (size_t)r * DIM;
  bf16x8 a_hi[4], a_lo[4];
#pragma unroll
  for (int ks = 0; ks < 4; ++ks) {
    f32x4 v0 = *(const f32x4*)(xr + ks * 32 + ko);
    f32x4 v1 = *(const f32x4*)(xr + ks * 32 + ko + 4);
    bf16x8 th, tl;
#pragma unroll
    for (int j = 0; j < 4; ++j) {
      th[j] = (__bf16)v0[j];     tl[j] = (__bf16)(v0[j] - (float)th[j]);
      th[4+j] = (__bf16)v1[j];   tl[4+j] = (__bf16)(v1[j] - (float)th[4+j]);
    }
    a_hi[ks] = th; a_lo[ks] = tl;
  }
  const f32x4 fz = {0.f, 0.f, 0.f, 0.f};
  f32x4 acc[8];
#pragma unroll
  for (int nf = 0; nf < 8; ++nf) acc[nf] = fz;
#pragma unroll
  for (int nf = 0; nf < 8; ++nf) {
    size_t wrow = (size_t)(nf * 16 + (lane & 15)) * DIM + ko;
    const __bf16* bh = encT_hi + wrow;
    const __bf16* bl = encT_lo + wrow;
#pragma unroll
    for (int ks = 0; ks < 4; ++ks) {
      bf16x8 wh = *(const bf16x8*)(bh + ks * 32);
      bf16x8 wl = *(const bf16x8*)(bl + ks * 32);
      acc[nf] = mfma16(a_hi[ks], wh, acc[nf]);
      acc[nf] = mfma16(a_lo[ks], wh, acc[nf]);
      acc[nf] = mfma16(a_hi[ks], wl, acc[nf]);
    }
  }
  int c0 = lane & 15;
  int rr = rbase + (lane >> 4) * 4;
#pragma unroll
  for (int nf = 0; nf < 8; ++nf) {
    int c = nf * 16 + c0;
    float bias = enc_b[c] + vn_emb[c];
#pragma unroll
    for (int j = 0; j < 4; ++j) {
      float v = acc[nf][j] + bias;
      h_in[(size_t)(rr + j) * DIM + c] = v;
      h_bf[(size_t)(rr + j) * DIM + c] = (__bf16)v;
    }
  }
}

// ---------------- per-graph pool: pooled = segsum(h_in) + vn ----------------
__global__ __launch_bounds__(1024) void k_pool(const float* __restrict__ h_in,
    const int* __restrict__ gs, const float* __restrict__ vn,
    float* __restrict__ pooled) {
  __shared__ float red[8][DIM];
  int g = blockIdx.x;
  int d = threadIdx.x & 127, slot = threadIdx.x >> 7;
  int lo = gs[g], hi = gs[g + 1];
  float acc = 0.f;
  for (int n = lo + slot; n < hi; n += 8)
    acc += h_in[(size_t)n * DIM + d];
  red[slot][d] = acc;
  __syncthreads();
  if (slot == 0) {
    float t = vn[g * DIM + d];
#pragma unroll
    for (int s2 = 0; s2 < 8; ++s2) t += red[s2][d];
    pooled[g * DIM + d] = t;
  }
}

// ---------------- GIN aggregation -> z (hi/lo split) ----------------
// 256 threads = 2 edge-slots x 128 channels; 4 gathers in flight (2 slots x unroll2)
__global__ __launch_bounds__(256) void k_agg(const __bf16* __restrict__ h_bf,
    const float* __restrict__ h_in,
    const int* __restrict__ offsets, const int* __restrict__ csr_src,
    const int* __restrict__ csr_eid, const float* __restrict__ edge_attr,
    const float* __restrict__ eW, const float* __restrict__ eB,
    const float* __restrict__ eps, int l,
    __bf16* __restrict__ z_hi, __bf16* __restrict__ z_lo) {
  __shared__ float ewl[EDIM * DIM];
  __shared__ float ebl[DIM];
  __shared__ float part[DIM];
  int tid = threadIdx.x;
  for (int idx = tid; idx < EDIM * DIM; idx += 256) ewl[idx] = eW[idx];
  if (tid < DIM) ebl[tid] = eB[tid];
  __syncthreads();
  int d = tid & 127, slot = tid >> 7;
  int n = blockIdx.x;
  int off = offsets[n], end = offsets[n + 1];
  float acc = 0.f;
  float eb = ebl[d];
  int i = off + slot;
  // slot s visits positions off+s, off+s+2, ... ; unroll 2 -> i and i+2
  for (; i + 2 < end; i += 4) {
    int s0 = csr_src[i],     e0 = csr_eid[i];
    int s1 = csr_src[i + 2], e1 = csr_eid[i + 2];
    const float* ea0 = edge_attr + (size_t)e0 * EDIM;
    const float* ea1 = edge_attr + (size_t)e1 * EDIM;
    float m0 = (float)h_bf[(size_t)s0 * DIM + d] + eb;
    float m1 = (float)h_bf[(size_t)s1 * DIM + d] + eb;
#pragma unroll
    for (int k = 0; k < EDIM; ++k) {
      m0 = fmaf(ea0[k], ewl[k * DIM + d], m0);
      m1 = fmaf(ea1[k], ewl[k * DIM + d], m1);
    }
    acc += fmaxf(m0, 0.f) + fmaxf(m1, 0.f);
  }
  for (; i < end; i += 2) {
    int s0 = csr_src[i], e0 = csr_eid[i];
    const float* ea0 = edge_attr + (size_t)e0 * EDIM;
    float m0 = (float)h_bf[(size_t)s0 * DIM + d] + eb;
#pragma unroll
    for (int k = 0; k < EDIM; ++k) m0 = fmaf(ea0[k], ewl[k * DIM + d], m0);
    acc += fmaxf(m0, 0.f);
  }
  if (slot == 1) part[d] = acc;
  __syncthreads();
  if (slot == 0) {
    float tot = acc + part[d];
    float v = (1.f + eps[l]) * h_in[(size_t)n * DIM + d] + tot;
    __bf16 hi = (__bf16)v;
    z_hi[(size_t)n * DIM + d] = hi;
    z_lo[(size_t)n * DIM + d] = (__bf16)(v - (float)hi);
  }
}

// ---------------- GEMM1: y1 = z @ W1 + b1 (+ BN1 stats), y1 f32 ----------------
__global__ __launch_bounds__(128) void k_gemm1(const __bf16* __restrict__ z_hi,
    const __bf16* __restrict__ z_lo,
    const __bf16* __restrict__ W1T_hi, const __bf16* __restrict__ W1T_lo,
    const float* __restrict__ b1,
    float* __restrict__ y1, float* __restrict__ sum1, float* __restrict__ sq1) {
  int lane = threadIdx.x & 63, wid = threadIdx.x >> 6;
  int rbase = blockIdx.x * 32 + wid * 16;
  int r = rbase + (lane & 15);
  int ko = (lane >> 4) * 8;
  bf16x8 a_hi[4], a_lo[4];
#pragma unroll
  for (int ks = 0; ks < 4; ++ks) {
    a_hi[ks] = *(const bf16x8*)(z_hi + (size_t)r * DIM + ks * 32 + ko);
    a_lo[ks] = *(const bf16x8*)(z_lo + (size_t)r * DIM + ks * 32 + ko);
  }
  const f32x4 fz = {0.f, 0.f, 0.f, 0.f};
  f32x4 acc[16];
#pragma unroll
  for (int nf = 0; nf < 16; ++nf) acc[nf] = fz;
#pragma unroll
  for (int nf = 0; nf < 16; ++nf) {
    size_t wrow = (size_t)(nf * 16 + (lane & 15)) * DIM + ko;
    const __bf16* bh = W1T_hi + wrow;
    const __bf16* bl = W1T_lo + wrow;
#pragma unroll
    for (int ks = 0; ks < 4; ++ks) {
      bf16x8 wh = *(const bf16x8*)(bh + ks * 32);
      bf16x8 wl = *(const bf16x8*)(bl + ks * 32);
      acc[nf] = mfma16(a_hi[ks], wh, acc[nf]);
      acc[nf] = mfma16(a_lo[ks], wh, acc[nf]);
      acc[nf] = mfma16(a_hi[ks], wl, acc[nf]);
    }
  }
  int c0 = lane & 15;
  int rr = rbase + (lane >> 4) * 4;
  int rep = blockIdx.x & 7;
#pragma unroll
  for (int nf = 0; nf < 16; ++nf) {
    int c = nf * 16 + c0;
    float bias = b1[c];
    float s = 0.f, q = 0.f;
#pragma unroll
    for (int j = 0; j < 4; ++j) {
      float v = acc[nf][j] + bias;
      y1[(size_t)(rr + j) * TWO_D + c] = v;
      s += v; q += v * v;
    }
    s += __shfl_xor(s, 16); s += __shfl_xor(s, 32);
    q += __shfl_xor(q, 16); q += __shfl_xor(q, 32);
    if (lane < 16) {
      atomicAdd(&sum1[rep * TWO_D + c], s);
      atomicAdd(&sq1[rep * TWO_D + c], q);
    }
  }
}

// ---------------- BN finalize ----------------
__global__ void k_fin(float* __restrict__ sum, float* __restrict__ sq,
    const float* __restrict__ g_, const float* __restrict__ b_,
    float* __restrict__ scale, float* __restrict__ shift, int C, float invN) {
  int c = threadIdx.x;
  if (c >= C) return;
  float s = 0.f, q = 0.f;
#pragma unroll
  for (int rep = 0; rep < 8; ++rep) {
    s += sum[rep * C + c]; sum[rep * C + c] = 0.f;
    q += sq[rep * C + c];  sq[rep * C + c]  = 0.f;
  }
  float m = s * invN;
  float var = q * invN - m * m;
  float a = g_[c] / sqrtf(var + 1e-5f);
  scale[c] = a;
  shift[c] = b_[c] - m * a;
}

// ---------------- GEMM2 ----------------
__global__ __launch_bounds__(128) void k_gemm2(const float* __restrict__ y1,
    const __bf16* __restrict__ W2T_hi, const __bf16* __restrict__ W2T_lo,
    const float* __restrict__ b2,
    const float* __restrict__ scale1, const float* __restrict__ shift1,
    float* __restrict__ y2, float* __restrict__ sum2, float* __restrict__ sq2) {
  int lane = threadIdx.x & 63, wid = threadIdx.x >> 6;
  int rbase = blockIdx.x * 32 + wid * 16;
  int r = rbase + (lane & 15);
  int ko = (lane >> 4) * 8;
  bf16x8 a_hi[8], a_lo[8];
#pragma unroll
  for (int ks = 0; ks < 8; ++ks) {
    int kb = ks * 32 + ko;
    f32x4 r0 = *(const f32x4*)(y1 + (size_t)r * TWO_D + kb);
    f32x4 r1 = *(const f32x4*)(y1 + (size_t)r * TWO_D + kb + 4);
    f32x4 sc0 = *(const f32x4*)(scale1 + kb);
    f32x4 sc1 = *(const f32x4*)(scale1 + kb + 4);
    f32x4 sh0 = *(const f32x4*)(shift1 + kb);
    f32x4 sh1 = *(const f32x4*)(shift1 + kb + 4);
    bf16x8 th, tl;
#pragma unroll
    for (int j = 0; j < 4; ++j) {
      float v0 = fmaxf(r0[j] * sc0[j] + sh0[j], 0.f);
      float v1 = fmaxf(r1[j] * sc1[j] + sh1[j], 0.f);
      th[j] = (__bf16)v0;     tl[j] = (__bf16)(v0 - (float)th[j]);
      th[4+j] = (__bf16)v1;   tl[4+j] = (__bf16)(v1 - (float)th[4+j]);
    }
    a_hi[ks] = th; a_lo[ks] = tl;
  }
  const f32x4 fz = {0.f, 0.f, 0.f, 0.f};
  f32x4 acc[8];
#pragma unroll
  for (int nf = 0; nf < 8; ++nf) acc[nf] = fz;
#pragma unroll
  for (int nf = 0; nf < 8; ++nf) {
    size_t wrow = (size_t)(nf * 16 + (lane & 15)) * TWO_D + ko;
    const __bf16* bh = W2T_hi + wrow;
    const __bf16* bl = W2T_lo + wrow;
#pragma unroll
    for (int ks = 0; ks < 8; ++ks) {
      bf16x8 wh = *(const bf16x8*)(bh + ks * 32);
      bf16x8 wl = *(const bf16x8*)(bl + ks * 32);
      acc[nf] = mfma16(a_hi[ks], wh, acc[nf]);
      acc[nf] = mfma16(a_lo[ks], wh, acc[nf]);
      acc[nf] = mfma16(a_hi[ks], wl, acc[nf]);
    }
  }
  int c0 = lane & 15;
  int rr = rbase + (lane >> 4) * 4;
  int rep = blockIdx.x & 7;
#pragma unroll
  for (int nf = 0; nf < 8; ++nf) {
    int c = nf * 16 + c0;
    float bias = b2[c];
    float s = 0.f, q = 0.f;
#pragma unroll
    for (int j = 0; j < 4; ++j) {
      float v = acc[nf][j] + bias;
      y2[(size_t)(rr + j) * DIM + c] = v;
      s += v; q += v * v;
    }
    s += __shfl_xor(s, 16); s += __shfl_xor(s, 32);
    q += __shfl_xor(q, 16); q += __shfl_xor(q, 32);
    if (lane < 16) {
      atomicAdd(&sum2[rep * DIM + c], s);
      atomicAdd(&sq2[rep * DIM + c], q);
    }
  }
}

// ---------------- virtual-node small GEMM / BN (f32, exact) ----------------
__global__ void k_vgemm(const float* __restrict__ in, const float* __restrict__ W,
    const float* __restrict__ bias, float* __restrict__ out, int K, int C) {
  __shared__ float row[TWO_D];
  int g = blockIdx.x;
  for (int k = threadIdx.x; k < K; k += blockDim.x) row[k] = in[g * K + k];
  __syncthreads();
  int c = threadIdx.x;
  if (c >= C) return;
  float acc = bias[c];
  for (int k = 0; k < K; ++k) acc = fmaf(row[k], W[k * C + c], acc);
  out[g * C + c] = acc;
}

__global__ void k_vbn(float* __restrict__ data, const float* __restrict__ g_,
    const float* __restrict__ b_, float* __restrict__ out, int C) {
  int c = threadIdx.x;
  if (c >= C) return;
  float s = 0.f, q = 0.f;
  for (int r = 0; r < NGRAPH; ++r) { float v = data[r * C + c]; s += v; q += v * v; }
  float m = s * (1.f / NGRAPH);
  float var = q * (1.f / NGRAPH) - m * m;
  float a = g_[c] / sqrtf(var + 1e-5f);
  float sh = b_[c] - m * a;
  for (int r = 0; r < NGRAPH; ++r)
    out[r * C + c] = fmaxf(data[r * C + c] * a + sh, 0.f);
}

// ---------------- fused BN2 + relu + vn gather -> next h_in (+ h_bf) ----------------
__global__ void k_bn2hin(const float* __restrict__ y2, const float* __restrict__ scale2,
    const float* __restrict__ shift2, const float* __restrict__ vn,
    const int* __restrict__ batch, float* __restrict__ h_in,
    __bf16* __restrict__ h_bf) {
  int idx = blockIdx.x * blockDim.x + threadIdx.x;
  if (idx >= N_NODES * (DIM / 4)) return;
  int c4 = idx & 31;
  int row = idx >> 5;
  f32x4 y = ((const f32x4*)y2)[idx];
  f32x4 sc = ((const f32x4*)scale2)[c4];
  f32x4 sh = ((const f32x4*)shift2)[c4];
  int b = batch[row];
  f32x4 v = ((const f32x4*)vn)[b * 32 + c4];
  f32x4 o;
  bf16x4 ob;
#pragma unroll
  for (int j = 0; j < 4; ++j) {
    o[j] = fmaxf(y[j] * sc[j] + sh[j], 0.f) + v[j];
    ob[j] = (__bf16)o[j];
  }
  ((f32x4*)h_in)[idx] = o;
  ((bf16x4*)h_bf)[idx] = ob;
}

__global__ void k_out(const float* __restrict__ y2, const float* __restrict__ scale2,
    const float* __restrict__ shift2, float* __restrict__ out) {
  int idx = blockIdx.x * blockDim.x + threadIdx.x;
  if (idx >= N_NODES * (DIM / 4)) return;
  int c4 = idx & 31;
  f32x4 y = ((const f32x4*)y2)[idx];
  f32x4 sc = ((const f32x4*)scale2)[c4];
  f32x4 sh = ((const f32x4*)shift2)[c4];
  f32x4 o;
#pragma unroll
  for (int j = 0; j < 4; ++j) o[j] = y[j] * sc[j] + sh[j];
  ((f32x4*)out)[idx] = o;
}

// ---------------- host ----------------
extern "C" void kernel_launch(void* const* d_in, const int* in_sizes, int n_in,
                              void* d_out, int out_size, void* d_ws, size_t ws_size,
                              hipStream_t stream) {
  const float* x         = (const float*)d_in[0];
  const float* edge_attr = (const float*)d_in[1];
  const int*   edge_index= (const int*)d_in[2];
  const int*   batch     = (const int*)d_in[3];
  const float* enc_W     = (const float*)d_in[4];
  const float* enc_b     = (const float*)d_in[5];
  const float* vn_emb    = (const float*)d_in[6];
  const float* eps       = (const float*)d_in[7];
  const float* edge_W    = (const float*)d_in[8];
  const float* edge_b    = (const float*)d_in[9];
  const float* mlp_W1    = (const float*)d_in[10];
  const float* mlp_b1    = (const float*)d_in[11];
  const float* mlp_bn1_g = (const float*)d_in[12];
  const float* mlp_bn1_b = (const float*)d_in[13];
  const float* mlp_W2    = (const float*)d_in[14];
  const float* mlp_b2    = (const float*)d_in[15];
  const float* bn_g      = (const float*)d_in[16];
  const float* bn_b      = (const float*)d_in[17];
  const float* vn_W1     = (const float*)d_in[18];
  const float* vn_b1     = (const float*)d_in[19];
  const float* vn_bn1_g  = (const float*)d_in[20];
  const float* vn_bn1_b  = (const float*)d_in[21];
  const float* vn_W2     = (const float*)d_in[22];
  const float* vn_b2     = (const float*)d_in[23];
  const float* vn_bn2_g  = (const float*)d_in[24];
  const float* vn_bn2_b  = (const float*)d_in[25];

  char* wsb = (char*)d_ws;
  size_t off = 0;
  auto take = [&](size_t bytes) -> void* {
    void* p = wsb + off;
    off += (bytes + 255) & ~(size_t)255;
    return p;
  };
  float*  h_in    = (float*)take((size_t)N_NODES * DIM * 4);
  float*  y2      = (float*)take((size_t)N_NODES * DIM * 4);
  float*  y1      = (float*)take((size_t)N_NODES * TWO_D * 4);
  // h_bf aliases y1: h_bf is only live between its producer (k_enc/k_bn2hin)
  // and k_agg, which both precede the k_gemm1 that overwrites y1; y1 is dead
  // by the time k_bn2hin rewrites h_bf.
  __bf16* h_bf    = (__bf16*)y1;
  __bf16* z_hi    = (__bf16*)take((size_t)N_NODES * DIM * 2);
  __bf16* z_lo    = (__bf16*)take((size_t)N_NODES * DIM * 2);
  int*    csr_src = (int*)take((size_t)N_EDGES * 4);
  int*    csr_eid = (int*)take((size_t)N_EDGES * 4);
  int*    counts  = (int*)take((size_t)2 * N_NODES * 4);
  int*    cursor  = counts + N_NODES;
  int*    offsets = (int*)take((size_t)(N_NODES + 1) * 4);
  int*    gs      = (int*)take((size_t)(NGRAPH + 1) * 4);
  float*  pooled  = (float*)take((size_t)NGRAPH * DIM * 4);
  float*  tv      = (float*)take((size_t)NGRAPH * TWO_D * 4);
  float*  vv      = (float*)take((size_t)NGRAPH * DIM * 4);
  float*  vn      = (float*)take((size_t)NGRAPH * DIM * 4);
  float*  sum1    = (float*)take(8 * TWO_D * 4);
  float*  sq1     = (float*)take(8 * TWO_D * 4);
  float*  sum2    = (float*)take(8 * DIM * 4);
  float*  sq2     = (float*)take(8 * DIM * 4);
  float*  scale1  = (float*)take(TWO_D * 4);
  float*  shift1  = (float*)take(TWO_D * 4);
  float*  scale2  = (float*)take(DIM * 4);
  float*  shift2  = (float*)take(DIM * 4);
  __bf16* encT_hi = (__bf16*)take((size_t)DIM * DIM * 2);
  __bf16* encT_lo = (__bf16*)take((size_t)DIM * DIM * 2);
  __bf16* W1T_hi  = (__bf16*)take((size_t)NLAYER * DIM * TWO_D * 2);
  __bf16* W1T_lo  = (__bf16*)take((size_t)NLAYER * DIM * TWO_D * 2);
  __bf16* W2T_hi  = (__bf16*)take((size_t)NLAYER * TWO_D * DIM * 2);
  __bf16* W2T_lo  = (__bf16*)take((size_t)NLAYER * TWO_D * DIM * 2);
  if (off > ws_size) return;

  const int* srcArr = edge_index;
  const int* dstArr = edge_index + N_EDGES;

  hipMemsetAsync(counts, 0, (size_t)2 * N_NODES * 4, stream);
  hipMemsetAsync(sum1, 0, (8 * TWO_D * 2 + 8 * DIM * 2) * 4, stream);

  k_hist<<<N_EDGES / 256, 256, 0, stream>>>(dstArr, counts);
  k_scan<<<1, 1024, 0, stream>>>(counts, offsets);
  k_fill<<<N_EDGES / 256, 256, 0, stream>>>(srcArr, dstArr, offsets, cursor, csr_src, csr_eid);
  k_gs<<<1, 256, 0, stream>>>(batch, gs);
  k_convT2<<<128, 256, 0, stream>>>(enc_W, encT_hi, encT_lo, DIM, DIM, 1);
  k_convT2<<<128, 256, 0, stream>>>(mlp_W1, W1T_hi, W1T_lo, DIM, TWO_D, NLAYER);
  k_convT2<<<128, 256, 0, stream>>>(mlp_W2, W2T_hi, W2T_lo, TWO_D, DIM, NLAYER);
  k_vninit<<<(NGRAPH * DIM) / 256, 256, 0, stream>>>(vn_emb, vn);
  k_enc<<<N_NODES / 32, 128, 0, stream>>>(x, encT_hi, encT_lo, enc_b, vn_emb, h_in, h_bf);

  for (int l = 0; l < NLAYER; ++l) {
    if (l < NLAYER - 1)
      k_pool<<<NGRAPH, 1024, 0, stream>>>(h_in, gs, vn, pooled);
    k_agg<<<N_NODES, 256, 0, stream>>>(h_bf, h_in, offsets, csr_src, csr_eid, edge_attr,
        edge_W + (size_t)l * EDIM * DIM, edge_b + (size_t)l * DIM, eps, l, z_hi, z_lo);
    k_gemm1<<<N_NODES / 32, 128, 0, stream>>>(z_hi, z_lo,
        W1T_hi + (size_t)l * DIM * TWO_D, W1T_lo + (size_t)l * DIM * TWO_D,
        mlp_b1 + (size_t)l * TWO_D, y1, sum1, sq1);
    k_fin<<<1, TWO_D, 0, stream>>>(sum1, sq1, mlp_bn1_g + (size_t)l * TWO_D,
        mlp_bn1_b + (size_t)l * TWO_D, scale1, shift1, TWO_D, 1.f / N_NODES);
    k_gemm2<<<N_NODES / 32, 128, 0, stream>>>(y1,
        W2T_hi + (size_t)l * TWO_D * DIM, W2T_lo + (size_t)l * TWO_D * DIM,
        mlp_b2 + (size_t)l * DIM, scale1, shift1, y2, sum2, sq2);
    k_fin<<<1, DIM, 0, stream>>>(sum2, sq2, bn_g + (size_t)l * DIM,
        bn_b + (size_t)l * DIM, scale2, shift2, DIM, 1.f / N_NODES);
    if (l < NLAYER - 1) {
      k_vgemm<<<NGRAPH, TWO_D, 0, stream>>>(pooled, vn_W1 + (size_t)l * DIM * TWO_D,
          vn_b1 + (size_t)l * TWO_D, tv, DIM, TWO_D);
      k_vbn<<<1, TWO_D, 0, stream>>>(tv, vn_bn1_g + (size_t)l * TWO_D,
          vn_bn1_b + (size_t)l * TWO_D, tv, TWO_D);
      k_vgemm<<<NGRAPH, DIM, 0, stream>>>(tv, vn_W2 + (size_t)l * TWO_D * DIM,
          vn_b2 + (size_t)l * DIM, vv, TWO_D, DIM);
      k_vbn<<<1, DIM, 0, stream>>>(vv, vn_bn2_g + (size_t)l * DIM,
          vn_bn2_b + (size_t)l * DIM, vn, DIM);
      k_bn2hin<<<(N_NODES * 32) / 256, 256, 0, stream>>>(y2, scale2, shift2, vn, batch, h_in, h_bf);
    } else {
      k_out<<<(N_NODES * 32) / 256, 256, 0, stream>>>(y2, scale2, shift2, (float*)d_out);
    }
  }
}